// Round 3
// baseline (226.111 us; speedup 1.0000x reference)
//
#include <hip/hip_runtime.h>
#include <stdint.h>
#include <stddef.h>

#define GLOBAL_AS __attribute__((address_space(1)))
#define LDS_AS    __attribute__((address_space(3)))

typedef __bf16 bf16x8 __attribute__((ext_vector_type(8)));
typedef float  f32x4  __attribute__((ext_vector_type(4)));

// x(8,256,64,64) fp32, W(128,256,4,4), bias(128,4,4), stride 2 -> out(8,128,130,130) fp32
constexpr int NB = 8, CI = 256, H_ = 64, W_ = 64, CO = 128;
constexpr int OH = 130, OW = 130;
constexpr int PU = 65;               // per-parity output extent u,v in [0,65)
constexpr int PAD = 66;              // padded x extent (zero border ring)
constexpr int NPIX = PU * PU;        // 4225 pixels per batch (per parity)
constexpr int NTOT = NB * NPIX;      // 33800 flat N
constexpr int NT_N = 133;            // ceil(33800/256)

constexpr size_t XPAD_ELEMS = (size_t)NB * PAD * PAD * CI;   // bf16
constexpr size_t XPAD_BYTES = XPAD_ELEMS * 2;                // 17,842,176
constexpr size_t WT_OFF     = XPAD_BYTES;
// A_all[512][1024]: row = py*256 + o*2 + px ; k = (a*2+c)*256 + i

__device__ __forceinline__ void gload_lds16(const void* g, void* l) {
  __builtin_amdgcn_global_load_lds((GLOBAL_AS void*)g, (LDS_AS void*)l, 16, 0, 0);
}

// ---- prep 1: x (b,i,h,w) fp32 -> x_padT[b][p][q][i] bf16, borders written as zeros here ----
__global__ void prep_x(const float* __restrict__ x, __bf16* __restrict__ xp) {
  __shared__ float tile[64][65];
  const int h   = blockIdx.x;          // 0..65 ; 64->zero row 0, 65->zero row 65
  const int bat = blockIdx.y;
  const int t   = threadIdx.x;         // 256
  if (h >= 64) {
    const int row = (h == 64) ? 0 : 65;
    __bf16* dst = xp + (size_t)(bat * PAD + row) * PAD * CI;
    bf16x8 z = {};
    for (int idx = t; idx < PAD * CI / 8; idx += 256)   // 2112 chunks
      *(bf16x8*)(dst + (size_t)idx * 8) = z;
    return;
  }
  // zero cols 0 and 65 of padded row h+1
  if (t < 64) {
    __bf16* rowp = xp + (size_t)(bat * PAD + h + 1) * PAD * CI;
    bf16x8 z = {};
    int half = t >> 5, part = t & 31;
    *(bf16x8*)(rowp + (size_t)half * 65 * CI + part * 8) = z;
  }
  for (int ch = 0; ch < 4; ++ch) {
    const int i0 = ch * 64;
    const float* src = x + (((size_t)(bat * CI + i0)) * H_ + h) * W_;
    if (ch) __syncthreads();
#pragma unroll
    for (int r = 0; r < 4; ++r) {
      int ii = r * 16 + (t >> 4);
      int ww = (t & 15) * 4;
      float4 v = *(const float4*)(src + (size_t)ii * H_ * W_ + ww);
      tile[ii][ww] = v.x; tile[ii][ww + 1] = v.y; tile[ii][ww + 2] = v.z; tile[ii][ww + 3] = v.w;
    }
    __syncthreads();
    __bf16* dst = xp + ((size_t)(bat * PAD + h + 1) * PAD + 1) * CI + i0;
#pragma unroll
    for (int r = 0; r < 2; ++r) {
      int s  = r * 256 + t;
      int ww = s >> 3;
      int ig = (s & 7) * 8;
      bf16x8 o;
#pragma unroll
      for (int k = 0; k < 8; ++k) o[k] = (__bf16)tile[ig + k][ww];
      *(bf16x8*)(dst + (size_t)ww * CI + ig) = o;
    }
  }
}

// ---- prep 2: W (o,i,ky,kx) fp32 -> A_all[(py*256 + o*2+px)*1024 + (a*2+c)*256 + i] bf16 ----
__global__ void prep_w2(const float* __restrict__ w, __bf16* __restrict__ wt2) {
  int tid = blockIdx.x * 256 + threadIdx.x;      // [0, 2^19)
  int i   = tid & 255;
  int tap = (tid >> 8) & 3;
  int row = (tid >> 10) & 255;
  int py  = tid >> 18;
  int a = tap >> 1, c = tap & 1;
  int o = row >> 1, px = row & 1;
  wt2[tid] = (__bf16)w[(size_t)(o * CI + i) * 16 + (py + 2 * a) * 4 + (px + 2 * c)];
}

// ---- main: BM=256 x BN=256, BK=64, counted-vmcnt double-buffered pipeline ----
__global__ __launch_bounds__(512, 2) void deconv_mfma(
    const __bf16* __restrict__ xp, const __bf16* __restrict__ wt2,
    const float* __restrict__ bias, float* __restrict__ out) {
  const int wg   = blockIdx.x;          // 266 = 2 * 133
  const int py   = wg / NT_N;
  const int nt_i = wg % NT_N;
  const int nBase = nt_i * 256;

  // per buf (64KB): A bytes [0,32768) = 256 rows x 64k ; B bytes [32768,65536) = 256 px x 64k
  __shared__ alignas(16) __bf16 lds[2][32768];   // 128 KiB total

  const int t    = threadIdx.x;
  const int wid  = t >> 6, lane = t & 63;
  const int lr   = lane & 15, kg = lane >> 4;
  const int wm   = wid >> 1, wn = wid & 1;       // 4 x 2 wave grid, wave tile 64(M) x 128(N)

  // ---- staging invariants: thread t stages chunks q = t + cc*512 (cc=0..3) of A and of B ----
  const int rowT = t >> 3;                        // 0..63 (+ cc*64)
  const int grp  = (t & 7) ^ ((t >> 3) & 7);      // logical k-octet at this phys slot (XOR involution)
  const __bf16* srcA = wt2 + ((size_t)(py * 256 + rowT)) * 1024 + grp * 8;  // + cc*64*1024 + s*64
  const __bf16* srcB[4];
#pragma unroll
  for (int cc = 0; cc < 4; ++cc) {
    int n = nBase + rowT + cc * 64;
    if (n > NTOT - 1) n = NTOT - 1;               // tail clamp (never stored)
    const int bat = n / NPIX, pr = n % NPIX;
    const int u = pr / PU, v = pr % PU;
    srcB[cc] = xp + ((size_t)(bat * PAD + u + 1) * PAD + (v + 1)) * CI + grp * 8;
  }

  // ---- fragment read byte-offsets (within lds[buf]), matching the staging swizzle ----
  int offA[2][4], offB[2][8];
#pragma unroll
  for (int ksub = 0; ksub < 2; ++ksub) {
    const int gx = ((ksub * 4 + kg) ^ (lr & 7)) * 16;
#pragma unroll
    for (int mt = 0; mt < 4; ++mt)
      offA[ksub][mt] = (wm * 64 + mt * 16 + lr) * 128 + gx;
#pragma unroll
    for (int nt = 0; nt < 8; ++nt)
      offB[ksub][nt] = 32768 + (wn * 128 + nt * 16 + lr) * 128 + gx;
  }

  f32x4 acc[4][8] = {};

  auto stage = [&](int buf, int s) {
    char* l = (char*)&lds[buf][0];
    const size_t koff = (size_t)s * 64;
#pragma unroll
    for (int cc = 0; cc < 4; ++cc)
      gload_lds16(srcA + (size_t)cc * 65536 + koff, l + (t + cc * 512) * 16);
    const int tap = s >> 2;                        // uniform per step (64 | 256)
    const int shift = ((tap >> 1) * PAD + (tap & 1)) * CI;
    const int ik = (s & 3) * 64;
#pragma unroll
    for (int cc = 0; cc < 4; ++cc)
      gload_lds16(srcB[cc] + ik - shift, l + 32768 + (t + cc * 512) * 16);
  };

  stage(0, 0);
  stage(1, 1);
  for (int s = 0; s < 16; ++s) {
    const int cur = s & 1;
    // wait only for tile s's 8 loads (tile s+1's 8 remain in flight) -> no drain
    if (s < 15) asm volatile("s_waitcnt vmcnt(8)" ::: "memory");
    else        asm volatile("s_waitcnt vmcnt(0)" ::: "memory");
    asm volatile("s_barrier" ::: "memory");        // publish buf[cur] to all waves
    const char* base = (const char*)&lds[cur][0];
#pragma unroll
    for (int ksub = 0; ksub < 2; ++ksub) {
      bf16x8 af[4], bfr[8];
#pragma unroll
      for (int mt = 0; mt < 4; ++mt) af[mt]  = *(const bf16x8*)(base + offA[ksub][mt]);
#pragma unroll
      for (int nt = 0; nt < 8; ++nt) bfr[nt] = *(const bf16x8*)(base + offB[ksub][nt]);
      __builtin_amdgcn_s_setprio(1);
#pragma unroll
      for (int mt = 0; mt < 4; ++mt)
#pragma unroll
        for (int nt = 0; nt < 8; ++nt)
          acc[mt][nt] = __builtin_amdgcn_mfma_f32_16x16x32_bf16(af[mt], bfr[nt], acc[mt][nt], 0, 0, 0);
      __builtin_amdgcn_s_setprio(0);
    }
    asm volatile("s_barrier" ::: "memory");        // all waves done reading buf[cur]
    if (s < 14) stage(cur, s + 2);                 // overwrite buf[cur] with tile s+2
  }

  // ---- epilogue: D rows r,r+1 are px=0,1 of same o -> dense float2 stores ----
#pragma unroll
  for (int mt = 0; mt < 4; ++mt) {
    const int rbase = wm * 64 + mt * 16 + kg * 4;  // D row = (lane>>4)*4 + r [m89-verified]
    const int o0 = rbase >> 1, o1 = o0 + 1;
#pragma unroll
    for (int nt = 0; nt < 8; ++nt) {
      const int n = nBase + wn * 128 + nt * 16 + lr;
      if (n < NTOT) {
        const int bat = n / NPIX, pr = n % NPIX;
        const int u = pr / PU, v = pr % PU;
        const int oy = 2 * u + py;
        const bool a0 = (u <= 63), a1 = (u >= 1);
        const bool c0 = (v <= 63), c1 = (v >= 1);
        auto bs = [&](int o, int px) {
          const float* bp = bias + (size_t)o * 16;
          float s0 = 0.f;
          if (a0 && c0) s0 += bp[py * 4 + px];
          if (a0 && c1) s0 += bp[py * 4 + px + 2];
          if (a1 && c0) s0 += bp[(py + 2) * 4 + px];
          if (a1 && c1) s0 += bp[(py + 2) * 4 + px + 2];
          return s0;
        };
        const size_t b0 = ((size_t)(bat * CO + o0) * OH + oy) * OW + 2 * v;
        const size_t b1 = ((size_t)(bat * CO + o1) * OH + oy) * OW + 2 * v;
        float2 w0, w1;
        w0.x = acc[mt][nt][0] + bs(o0, 0);
        w0.y = acc[mt][nt][1] + bs(o0, 1);
        w1.x = acc[mt][nt][2] + bs(o1, 0);
        w1.y = acc[mt][nt][3] + bs(o1, 1);
        *(float2*)(out + b0) = w0;
        *(float2*)(out + b1) = w1;
      }
    }
  }
}

extern "C" void kernel_launch(void* const* d_in, const int* in_sizes, int n_in,
                              void* d_out, int out_size, void* d_ws, size_t ws_size,
                              hipStream_t stream) {
  const float* x    = (const float*)d_in[0];
  const float* w    = (const float*)d_in[1];
  const float* bias = (const float*)d_in[2];
  float* out = (float*)d_out;
  char* ws = (char*)d_ws;
  __bf16* xpad = (__bf16*)ws;
  __bf16* wt2  = (__bf16*)(ws + WT_OFF);

  prep_x<<<dim3(66, 8), 256, 0, stream>>>(x, xpad);     // writes borders itself (no memset)
  prep_w2<<<dim3(2048), 256, 0, stream>>>(w, wt2);
  deconv_mfma<<<dim3(2 * NT_N), 512, 0, stream>>>(xpad, wt2, bias, out);
}

// Round 4
// 203.397 us; speedup vs baseline: 1.1117x; 1.1117x over previous
//
#include <hip/hip_runtime.h>
#include <stdint.h>
#include <stddef.h>

#define GLOBAL_AS __attribute__((address_space(1)))
#define LDS_AS    __attribute__((address_space(3)))

typedef __bf16 bf16x8 __attribute__((ext_vector_type(8)));
typedef float  f32x4  __attribute__((ext_vector_type(4)));

// x(8,256,64,64) fp32, W(128,256,4,4), bias(128,4,4), stride 2 -> out(8,128,130,130) fp32
constexpr int NB = 8, CI = 256, H_ = 64, W_ = 64, CO = 128;
constexpr int OH = 130, OW = 130;
constexpr int PU = 65;               // per-parity output extent u,v in [0,65)
constexpr int PAD = 66;              // padded x extent (zero border ring)
constexpr int NPIX = PU * PU;        // 4225 pixels per batch per parity
constexpr int NTOT = NB * NPIX;      // 33800 flat N
constexpr int NT_N = 265;            // ceil(33800/128)

// workspace layout (bytes)
constexpr size_t XPAD_BYTES = (size_t)NB * PAD * PAD * CI * 2;    // 17,842,176
constexpr size_t A_OFF      = XPAD_BYTES;                          // A_all[512][1024] bf16 = 1 MiB
constexpr size_t A_BYTES    = (size_t)512 * 1024 * 2;
constexpr size_t B_OFF      = A_OFF + A_BYTES;                     // Bmat[33800][1024] bf16 = 69.2 MB
// total ~88.1 MB

__device__ __forceinline__ void gload_lds16(const void* g, void* l) {
  __builtin_amdgcn_global_load_lds((GLOBAL_AS void*)g, (LDS_AS void*)l, 16, 0, 0);
}

// ---- P1: x (b,i,h,w) fp32 -> xpadT[b][p][q][i] bf16, zero border ring written here ----
__global__ void prep_x(const float* __restrict__ x, __bf16* __restrict__ xp) {
  __shared__ float tile[64][65];
  const int h   = blockIdx.x;          // 0..65 ; 64 -> zero row 0, 65 -> zero row 65
  const int bat = blockIdx.y;
  const int t   = threadIdx.x;         // 256
  if (h >= 64) {
    const int row = (h == 64) ? 0 : 65;
    __bf16* dst = xp + (size_t)(bat * PAD + row) * PAD * CI;
    bf16x8 z = {};
    for (int idx = t; idx < PAD * CI / 8; idx += 256)
      *(bf16x8*)(dst + (size_t)idx * 8) = z;
    return;
  }
  if (t < 64) {   // zero cols 0 and 65 of padded row h+1
    __bf16* rowp = xp + (size_t)(bat * PAD + h + 1) * PAD * CI;
    bf16x8 z = {};
    int half = t >> 5, part = t & 31;
    *(bf16x8*)(rowp + (size_t)half * 65 * CI + part * 8) = z;
  }
  for (int ch = 0; ch < 4; ++ch) {
    const int i0 = ch * 64;
    const float* src = x + (((size_t)(bat * CI + i0)) * H_ + h) * W_;
    if (ch) __syncthreads();
#pragma unroll
    for (int r = 0; r < 4; ++r) {
      int ii = r * 16 + (t >> 4);
      int ww = (t & 15) * 4;
      float4 v = *(const float4*)(src + (size_t)ii * H_ * W_ + ww);
      tile[ii][ww] = v.x; tile[ii][ww + 1] = v.y; tile[ii][ww + 2] = v.z; tile[ii][ww + 3] = v.w;
    }
    __syncthreads();
    __bf16* dst = xp + ((size_t)(bat * PAD + h + 1) * PAD + 1) * CI + i0;
#pragma unroll
    for (int r = 0; r < 2; ++r) {
      int s  = r * 256 + t;
      int ww = s >> 3;
      int ig = (s & 7) * 8;
      bf16x8 o;
#pragma unroll
      for (int k = 0; k < 8; ++k) o[k] = (__bf16)tile[ig + k][ww];
      *(bf16x8*)(dst + (size_t)ww * CI + ig) = o;
    }
  }
}

// ---- P2: build Bmat[n][k] (gather, branch-free via zero ring) + A_all[m][k] ----
// Bmat row n=(bat,u,v): k = tap*256+i <- xpadT[bat][u+1-a][v+1-c][i]
// A_all row m = py*256 + o*2 + px:    k = tap*256+i <- W[o][i][py+2a][px+2c]
__global__ void build_ab(const float* __restrict__ w, const __bf16* __restrict__ xp,
                         __bf16* __restrict__ amat, __bf16* __restrict__ bmat) {
  const int bid = blockIdx.x;
  const int t   = threadIdx.x;
  if (bid < 16900) {                       // B: 33800 rows x 128 chunks of 16B
    const int g = bid * 256 + t;
    const int n = g >> 7, c = g & 127;
    const int tap = c >> 5, ic = c & 31;
    const int a = tap >> 1, cc = tap & 1;
    const int bat = n / NPIX, pr = n % NPIX;
    const int u = pr / PU, v = pr % PU;
    const __bf16* src = xp + (((size_t)(bat * PAD + u + 1 - a)) * PAD + (v + 1 - cc)) * CI + ic * 8;
    *(bf16x8*)(bmat + (size_t)n * 1024 + (size_t)c * 8) = *(const bf16x8*)src;
  } else {                                 // A: 524288 scalar elems
    const int tid = (bid - 16900) * 256 + t;
    const int i   = tid & 255;
    const int tap = (tid >> 8) & 3;
    const int row = (tid >> 10) & 255;
    const int py  = tid >> 18;
    const int a = tap >> 1, c = tap & 1;
    const int o = row >> 1, px = row & 1;
    amat[tid] = (__bf16)w[(size_t)(o * CI + i) * 16 + (py + 2 * a) * 4 + (px + 2 * c)];
  }
}

// ---- main: m97-geometry GEMM. 128x128 tile, BK=32, 4 waves, 32KB LDS, 5 blocks/CU ----
__global__ __launch_bounds__(256) void deconv_mfma(
    const __bf16* __restrict__ amat, const __bf16* __restrict__ bmat,
    const float* __restrict__ bias, float* __restrict__ out) {
  // wg: mt_i = wg & 3 (M-tile of 128), nt_i = wg >> 2 (N-tile of 128); 4*265 = 1060
  const int wg   = blockIdx.x;
  const int mt_i = wg & 3;
  const int nt_i = wg >> 2;
  const int nBase = nt_i * 128;

  __shared__ alignas(16) __bf16 lds[2][8192];  // per buf: A [0,4096) 128m x 32k, B [4096,8192) 128n x 32k

  const int t    = threadIdx.x;
  const int wid  = t >> 6, lane = t & 63;
  const int lr   = lane & 15, kg = lane >> 4;
  const int wr   = wid >> 1, wc = wid & 1;     // 2x2 waves, 64x64 each

  // staging: thread t stages chunks q=t and q=t+256 of A and of B
  const int m0   = t >> 2;                      // 0..63 (chunk2: +64, same swizzle phase)
  const int kst  = (t & 3) ^ ((m0 >> 1) & 3);   // XOR involution (r2-verified)
  const __bf16* srcA  = amat + ((size_t)(mt_i * 128 + m0)) * 1024 + kst * 8;
  int nA = nBase + m0;       if (nA > NTOT - 1) nA = NTOT - 1;
  int nB2 = nBase + m0 + 64; if (nB2 > NTOT - 1) nB2 = NTOT - 1;
  const __bf16* srcB  = bmat + (size_t)nA  * 1024 + kst * 8;
  const __bf16* srcB2 = bmat + (size_t)nB2 * 1024 + kst * 8;

  // fragment read offsets (elems within lds[buf]), matching the staging swizzle (r2-verified)
  const int swz = (lr >> 1) & 3;
  int offA[4], offB[4];
#pragma unroll
  for (int mt = 0; mt < 4; ++mt)
    offA[mt] = (wr * 64 + mt * 16 + lr) * 32 + ((kg ^ swz) * 8);
#pragma unroll
  for (int nt = 0; nt < 4; ++nt)
    offB[nt] = 4096 + (wc * 64 + nt * 16 + lr) * 32 + ((kg ^ swz) * 8);

  f32x4 acc[4][4] = {};

  auto stage = [&](int buf, int s) {
    const size_t ko = (size_t)s * 32;
    __bf16* l = &lds[buf][0];
    gload_lds16(srcA  + ko,              l + (size_t)t * 8);
    gload_lds16(srcA  + 64 * 1024 + ko,  l + (size_t)t * 8 + 2048);
    gload_lds16(srcB  + ko,              l + 4096 + (size_t)t * 8);
    gload_lds16(srcB2 + ko,              l + 4096 + (size_t)t * 8 + 2048);
  };

  stage(0, 0);
  __syncthreads();
  int cur = 0;
  for (int s = 0; s < 32; ++s) {
    if (s < 31) stage(cur ^ 1, s + 1);     // issue next-tile loads early
    const __bf16* base = &lds[cur][0];
    bf16x8 af[4], bfr[4];
#pragma unroll
    for (int mt = 0; mt < 4; ++mt) af[mt]  = *(const bf16x8*)(base + offA[mt]);
#pragma unroll
    for (int nt = 0; nt < 4; ++nt) bfr[nt] = *(const bf16x8*)(base + offB[nt]);
#pragma unroll
    for (int mt = 0; mt < 4; ++mt)
#pragma unroll
      for (int nt = 0; nt < 4; ++nt)
        acc[mt][nt] = __builtin_amdgcn_mfma_f32_16x16x32_bf16(af[mt], bfr[nt], acc[mt][nt], 0, 0, 0);
    __syncthreads();
    cur ^= 1;
  }

  // ---- epilogue: D rows r,r+1 are px=0,1 of same o -> dense float2 stores (r2-verified) ----
  const int py = mt_i >> 1;
#pragma unroll
  for (int mt = 0; mt < 4; ++mt) {
    const int rbase = (mt_i & 1) * 128 + wr * 64 + mt * 16 + kg * 4;  // within py's 256 rows
    const int o0 = rbase >> 1, o1 = o0 + 1;
#pragma unroll
    for (int nt = 0; nt < 4; ++nt) {
      const int n = nBase + wc * 64 + nt * 16 + lr;
      if (n < NTOT) {
        const int bat = n / NPIX, pr = n % NPIX;
        const int u = pr / PU, v = pr % PU;
        const int oy = 2 * u + py;
        const bool a0 = (u <= 63), a1 = (u >= 1);
        const bool c0 = (v <= 63), c1 = (v >= 1);
        auto bs = [&](int o, int px) {
          const float* bp = bias + (size_t)o * 16;
          float s0 = 0.f;
          if (a0 && c0) s0 += bp[py * 4 + px];
          if (a0 && c1) s0 += bp[py * 4 + px + 2];
          if (a1 && c0) s0 += bp[(py + 2) * 4 + px];
          if (a1 && c1) s0 += bp[(py + 2) * 4 + px + 2];
          return s0;
        };
        const size_t b0 = ((size_t)(bat * CO + o0) * OH + oy) * OW + 2 * v;
        const size_t b1 = ((size_t)(bat * CO + o1) * OH + oy) * OW + 2 * v;
        float2 w0, w1;
        w0.x = acc[mt][nt][0] + bs(o0, 0);
        w0.y = acc[mt][nt][1] + bs(o0, 1);
        w1.x = acc[mt][nt][2] + bs(o1, 0);
        w1.y = acc[mt][nt][3] + bs(o1, 1);
        *(float2*)(out + b0) = w0;
        *(float2*)(out + b1) = w1;
      }
    }
  }
}

extern "C" void kernel_launch(void* const* d_in, const int* in_sizes, int n_in,
                              void* d_out, int out_size, void* d_ws, size_t ws_size,
                              hipStream_t stream) {
  const float* x    = (const float*)d_in[0];
  const float* w    = (const float*)d_in[1];
  const float* bias = (const float*)d_in[2];
  float* out = (float*)d_out;
  char* ws = (char*)d_ws;
  __bf16* xpad = (__bf16*)ws;
  __bf16* amat = (__bf16*)(ws + A_OFF);
  __bf16* bmat = (__bf16*)(ws + B_OFF);

  prep_x<<<dim3(66, 8), 256, 0, stream>>>(x, xpad);
  build_ab<<<dim3(16900 + 2048), 256, 0, stream>>>(w, xpad, amat, bmat);
  deconv_mfma<<<dim3(4 * NT_N), 256, 0, stream>>>(amat, bmat, bias, out);
}